// Round 3
// baseline (126.999 us; speedup 1.0000x reference)
//
#include <hip/hip_runtime.h>

#define TSTEPS 1024
#define NROWS  8192
#define CLEN   16      // steps per chunk = steps per lane
#define KEPS   1e-6f

typedef float f32x4 __attribute__((ext_vector_type(4)));
typedef int   i32x4 __attribute__((ext_vector_type(4)));

__device__ __forceinline__ float clampP(float x) {
    return fminf(fmaxf(x, KEPS), 1.f - KEPS);
}
__device__ __forceinline__ float sigm(float v) {
    return 1.0f / (1.0f + __expf(-v));
}

// ---------------- K1: per-row MLP -> params {l,g,s,prior}; 4 rows/wave, 16 rows/block ----
__global__ __launch_bounds__(256) void bkt_params_v4(
    const int* __restrict__ X, const float* __restrict__ embed,
    const float* __restrict__ W0, const float* __restrict__ b0,
    const float* __restrict__ W1, const float* __restrict__ b1,
    const float* __restrict__ Wout, const float* __restrict__ bout,
    float4* __restrict__ params)
{
    const int lane    = threadIdx.x & 63;
    const int wid     = threadIdx.x >> 6;
    const int rowbase = blockIdx.x * 16 + wid * 4;

    __shared__ float sh[4][4][64];
    float (*shw)[64] = sh[wid];

    #pragma unroll
    for (int rs = 0; rs < 4; ++rs) {
        const int skill = X[rowbase + rs];
        shw[rs][lane] = embed[(size_t)skill * 64 + lane];
    }
    __syncthreads();

    float a0 = b0[lane], a1 = a0, a2 = a0, a3 = a0;
    #pragma unroll
    for (int k4 = 0; k4 < 16; ++k4) {
        const float4 e0 = *(const float4*)&shw[0][k4 * 4];
        const float4 e1 = *(const float4*)&shw[1][k4 * 4];
        const float4 e2 = *(const float4*)&shw[2][k4 * 4];
        const float4 e3 = *(const float4*)&shw[3][k4 * 4];
        const float w0 = W0[(k4 * 4 + 0) * 64 + lane];
        const float w1 = W0[(k4 * 4 + 1) * 64 + lane];
        const float w2 = W0[(k4 * 4 + 2) * 64 + lane];
        const float w3 = W0[(k4 * 4 + 3) * 64 + lane];
        a0 = fmaf(e0.x, w0, a0); a0 = fmaf(e0.y, w1, a0); a0 = fmaf(e0.z, w2, a0); a0 = fmaf(e0.w, w3, a0);
        a1 = fmaf(e1.x, w0, a1); a1 = fmaf(e1.y, w1, a1); a1 = fmaf(e1.z, w2, a1); a1 = fmaf(e1.w, w3, a1);
        a2 = fmaf(e2.x, w0, a2); a2 = fmaf(e2.y, w1, a2); a2 = fmaf(e2.z, w2, a2); a2 = fmaf(e2.w, w3, a2);
        a3 = fmaf(e3.x, w0, a3); a3 = fmaf(e3.y, w1, a3); a3 = fmaf(e3.z, w2, a3); a3 = fmaf(e3.w, w3, a3);
    }
    __syncthreads();
    shw[0][lane] = fmaxf(a0, 0.f);
    shw[1][lane] = fmaxf(a1, 0.f);
    shw[2][lane] = fmaxf(a2, 0.f);
    shw[3][lane] = fmaxf(a3, 0.f);
    __syncthreads();

    a0 = b1[lane]; a1 = a0; a2 = a0; a3 = a0;
    #pragma unroll
    for (int k4 = 0; k4 < 16; ++k4) {
        const float4 e0 = *(const float4*)&shw[0][k4 * 4];
        const float4 e1 = *(const float4*)&shw[1][k4 * 4];
        const float4 e2 = *(const float4*)&shw[2][k4 * 4];
        const float4 e3 = *(const float4*)&shw[3][k4 * 4];
        const float w0 = W1[(k4 * 4 + 0) * 64 + lane];
        const float w1 = W1[(k4 * 4 + 1) * 64 + lane];
        const float w2 = W1[(k4 * 4 + 2) * 64 + lane];
        const float w3 = W1[(k4 * 4 + 3) * 64 + lane];
        a0 = fmaf(e0.x, w0, a0); a0 = fmaf(e0.y, w1, a0); a0 = fmaf(e0.z, w2, a0); a0 = fmaf(e0.w, w3, a0);
        a1 = fmaf(e1.x, w0, a1); a1 = fmaf(e1.y, w1, a1); a1 = fmaf(e1.z, w2, a1); a1 = fmaf(e1.w, w3, a1);
        a2 = fmaf(e2.x, w0, a2); a2 = fmaf(e2.y, w1, a2); a2 = fmaf(e2.z, w2, a2); a2 = fmaf(e2.w, w3, a2);
        a3 = fmaf(e3.x, w0, a3); a3 = fmaf(e3.y, w1, a3); a3 = fmaf(e3.z, w2, a3); a3 = fmaf(e3.w, w3, a3);
    }
    const float h0r = fmaxf(a0, 0.f), h1r = fmaxf(a1, 0.f);
    const float h2r = fmaxf(a2, 0.f), h3r = fmaxf(a3, 0.f);

    const float4 wo = ((const float4*)Wout)[lane];
    float p[4][4];
    p[0][0] = h0r * wo.x; p[0][1] = h0r * wo.y; p[0][2] = h0r * wo.z; p[0][3] = h0r * wo.w;
    p[1][0] = h1r * wo.x; p[1][1] = h1r * wo.y; p[1][2] = h1r * wo.z; p[1][3] = h1r * wo.w;
    p[2][0] = h2r * wo.x; p[2][1] = h2r * wo.y; p[2][2] = h2r * wo.z; p[2][3] = h2r * wo.w;
    p[3][0] = h3r * wo.x; p[3][1] = h3r * wo.y; p[3][2] = h3r * wo.z; p[3][3] = h3r * wo.w;
    #pragma unroll
    for (int off = 32; off >= 1; off >>= 1) {
        #pragma unroll
        for (int rs = 0; rs < 4; ++rs)
            #pragma unroll
            for (int c = 0; c < 4; ++c)
                p[rs][c] += __shfl_xor(p[rs][c], off, 64);
    }
    const float4 bo = *(const float4*)bout;
    float v0 = (lane == 0) ? p[0][0] : (lane == 1) ? p[1][0] : (lane == 2) ? p[2][0] : p[3][0];
    float v1 = (lane == 0) ? p[0][1] : (lane == 1) ? p[1][1] : (lane == 2) ? p[2][1] : p[3][1];
    float v2 = (lane == 0) ? p[0][2] : (lane == 1) ? p[1][2] : (lane == 2) ? p[2][2] : p[3][2];
    float v3 = (lane == 0) ? p[0][3] : (lane == 1) ? p[1][3] : (lane == 2) ? p[2][3] : p[3][3];
    if (lane < 4) {
        float4 r;
        r.x = clampP(sigm(v0 + bo.x));
        r.y = clampP(sigm(v1 + bo.y));
        r.z = clampP(sigm(v2 + bo.z));
        r.w = clampP(sigm(v3 + bo.w));
        params[rowbase + lane] = r;
    }
}

// ---------------- K2: one wave per row; lane = 16-step time chunk ----------------
// v6b: halved LDS (single wave-private transpose buffer, write-through + recompute),
//      no __syncthreads (buffer is wave-private; within-wave DS ordering is program
//      order), 1 rcp per recurrence step, nontemporal loads/stores (ext_vector types).
//      Target: 8 blocks/CU (VGPR<=64 via launch_bounds min-waves=8).
__global__ __launch_bounds__(256, 8) void bkt_scan_v6(
    const int* __restrict__ y, const float4* __restrict__ params,
    float* __restrict__ out_corr, float* __restrict__ out_lat)
{
    const int lane = threadIdx.x & 63;
    const int wid  = threadIdx.x >> 6;
    const int row  = blockIdx.x * 4 + wid;

    // Per-wave transpose buffer: stride 17 floats -> 2-way bank aliasing (free).
    __shared__ float shbuf[4][64 * 17];   // 17408 B total
    float* shw = shbuf[wid];

    const float4 p = params[row];
    const float l = p.x, g = p.y, s = p.z, prior = p.w;

    // ---- Phase A: coalesced y loads (4 x 1KB contiguous per wave) ----
    // load j, lane i holds y[t] for t = j*256 + 4i + e (e=0..3)
    const i32x4* yrow = (const i32x4*)(y + (size_t)row * TSTEPS);
    unsigned long long B[4][4];
    #pragma unroll
    for (int j = 0; j < 4; ++j) {
        const i32x4 v = __builtin_nontemporal_load(&yrow[j * 64 + lane]);
        B[j][0] = __ballot(v.x > 0);
        B[j][1] = __ballot(v.y > 0);
        B[j][2] = __ballot(v.z > 0);
        B[j][3] = __ballot(v.w > 0);
    }
    // chunk c = lane owns t = 16c+q. bit q lives at ballot[j=c>>4][e=q&3],
    // bit index 4*(c&15) + (q>>2). Gather 4-bit nibble per e, spread k->4k.
    const int jsel  = lane >> 4;
    const int ibase = (lane & 15) * 4;
    unsigned msk = 0;
    #pragma unroll
    for (int e = 0; e < 4; ++e) {
        const unsigned long long be =
            (jsel == 0) ? B[0][e] : (jsel == 1) ? B[1][e] :
            (jsel == 2) ? B[2][e] : B[3][e];
        const unsigned n  = (unsigned)(be >> ibase) & 0xFu;
        const unsigned sp = (n & 1u) | ((n & 2u) << 3) | ((n & 4u) << 6) | ((n & 8u) << 9);
        msk |= sp << e;
    }

    // step as Mobius: L' = (m00*L+m01)/(m10*L+m11)
    const float c1 = 1.f - s - g, d1 = g;             // y=1 denominator coeffs
    const float e00_1 = fmaf(l, c1, (1.f - l) * (1.f - s));
    const float e01_1 = l * d1;
    const float c0 = s + g - 1.f, d0 = 1.f - g;       // y=0
    const float e00_0 = fmaf(l, c0, (1.f - l) * s);
    const float e01_0 = l * d0;

    // Phase C: compose my chunk's 16 step matrices (renorm every 4; m11 > 0)
    float m00 = 1.f, m01 = 0.f, m10 = 0.f, m11 = 1.f;
    #pragma unroll
    for (int t = 0; t < CLEN; ++t) {
        const bool one = (msk >> t) & 1u;
        const float e00 = one ? e00_1 : e00_0;
        const float e01 = one ? e01_1 : e01_0;
        const float e10 = one ? c1 : c0;
        const float e11 = one ? d1 : d0;
        const float n00 = fmaf(e00, m00, e01 * m10);
        const float n01 = fmaf(e00, m01, e01 * m11);
        const float n10 = fmaf(e10, m00, e11 * m10);
        const float n11 = fmaf(e10, m01, e11 * m11);
        if ((t & 3) == 3) {
            const float inv = __builtin_amdgcn_rcpf(n11);
            m00 = n00 * inv; m01 = n01 * inv; m10 = n10 * inv; m11 = 1.f;
        } else {
            m00 = n00; m01 = n01; m10 = n10; m11 = n11;
        }
    }

    // Phase D: inclusive Hillis-Steele prefix over the 64 chunk matrices
    float s00 = m00, s01 = m01, s10 = m10, s11 = m11;
    #pragma unroll
    for (int d = 1; d < 64; d <<= 1) {
        const float t00 = __shfl_up(s00, d, 64);
        const float t01 = __shfl_up(s01, d, 64);
        const float t10 = __shfl_up(s10, d, 64);
        const float t11 = __shfl_up(s11, d, 64);
        if (lane >= d) {
            const float r00 = fmaf(s00, t00, s01 * t10);
            const float r01 = fmaf(s00, t01, s01 * t11);
            const float r10 = fmaf(s10, t00, s11 * t10);
            const float r11 = fmaf(s10, t01, s11 * t11);
            const float inv = __builtin_amdgcn_rcpf(r11);
            s00 = r00 * inv; s01 = r01 * inv; s10 = r10 * inv; s11 = 1.f;
        }
    }
    // exclusive prefix -> my chunk-start latent
    const float x00 = __shfl_up(s00, 1, 64);
    const float x01 = __shfl_up(s01, 1, 64);
    const float x10 = __shfl_up(s10, 1, 64);
    const float x11 = __shfl_up(s11, 1, 64);
    float L0;
    if (lane == 0) {
        L0 = prior;
    } else {
        const float num = fmaf(x00, prior, x01);
        const float den = fmaf(x10, prior, x11);
        L0 = clampP(num * __builtin_amdgcn_rcpf(den));
    }

    // Phase E/F pass 1: recurrence, write `correct` through to LDS, store time-major.
    // (buffer is wave-private: lanes of one wave share one instruction stream, so
    //  ds_write -> ds_read ordering is program order; no block barrier needed)
    const float a   = 1.f - s;
    const float omg = 1.f - g;
    const float oml = 1.f - l;
    float* oc = out_corr + (size_t)row * TSTEPS;
    float* ol = out_lat  + (size_t)row * TSTEPS;

    float Lc = L0;
    #pragma unroll
    for (int t = 0; t < CLEN; ++t) {
        const float correct = fmaf(Lc, c1, g);    // L*(1-s-g)+g
        const float den0    = fmaf(Lc, c0, omg);  // L*(s+g-1)+(1-g)
        shw[lane * 17 + t] = correct;
        const bool one = (msk >> t) & 1u;
        const float den = one ? correct : den0;
        const float num = Lc * (one ? a : s);
        const float k   = num * __builtin_amdgcn_rcpf(den);
        Lc = clampP(fmaf(k, oml, l));
    }
    #pragma unroll
    for (int j = 0; j < 4; ++j) {
        const int c    = j * 16 + (lane >> 2);
        const int q    = (lane & 3) * 4;
        const int base = c * 17 + q;
        f32x4 vc;
        vc.x = shw[base + 0]; vc.y = shw[base + 1]; vc.z = shw[base + 2]; vc.w = shw[base + 3];
        __builtin_nontemporal_store(vc, (f32x4*)(oc + j * 256 + lane * 4));
    }

    // Pass 2: re-run the (cheap) recurrence, write `latent` through, store.
    Lc = L0;
    #pragma unroll
    for (int t = 0; t < CLEN; ++t) {
        const float correct = fmaf(Lc, c1, g);
        const float den0    = fmaf(Lc, c0, omg);
        shw[lane * 17 + t] = Lc;
        const bool one = (msk >> t) & 1u;
        const float den = one ? correct : den0;
        const float num = Lc * (one ? a : s);
        const float k   = num * __builtin_amdgcn_rcpf(den);
        Lc = clampP(fmaf(k, oml, l));
    }
    #pragma unroll
    for (int j = 0; j < 4; ++j) {
        const int c    = j * 16 + (lane >> 2);
        const int q    = (lane & 3) * 4;
        const int base = c * 17 + q;
        f32x4 vl;
        vl.x = shw[base + 0]; vl.y = shw[base + 1]; vl.z = shw[base + 2]; vl.w = shw[base + 3];
        __builtin_nontemporal_store(vl, (f32x4*)(ol + j * 256 + lane * 4));
    }
}

extern "C" void kernel_launch(void* const* d_in, const int* in_sizes, int n_in,
                              void* d_out, int out_size, void* d_ws, size_t ws_size,
                              hipStream_t stream) {
    const int*   X     = (const int*)  d_in[0];
    const int*   y     = (const int*)  d_in[1];
    const float* embed = (const float*)d_in[2];
    const float* W0    = (const float*)d_in[3];
    const float* b0    = (const float*)d_in[4];
    const float* W1    = (const float*)d_in[5];
    const float* b1    = (const float*)d_in[6];
    const float* Wout  = (const float*)d_in[7];
    const float* bout  = (const float*)d_in[8];

    float* out_corr = (float*)d_out;
    float* out_lat  = out_corr + (size_t)NROWS * TSTEPS;
    float4* paramsb = (float4*)d_ws;   // 128 KB scratch

    bkt_params_v4<<<NROWS / 16, 256, 0, stream>>>(X, embed, W0, b0, W1, b1, Wout, bout, paramsb);
    bkt_scan_v6 <<<NROWS / 4,  256, 0, stream>>>(y, paramsb, out_corr, out_lat);
}

// Round 4
// 121.732 us; speedup vs baseline: 1.0433x; 1.0433x over previous
//
#include <hip/hip_runtime.h>

#define TSTEPS 1024
#define NROWS  8192
#define CLEN   16      // steps per chunk = steps per lane
#define KEPS   1e-6f

__device__ __forceinline__ float clampP(float x) {
    return fminf(fmaxf(x, KEPS), 1.f - KEPS);
}
__device__ __forceinline__ float sigm(float v) {
    return 1.0f / (1.0f + __expf(-v));
}

// ---------------- Fused kernel: one wave per row, zero barriers ----------------
// Per wave: (1) issue y loads, (2) solo MLP for its row (params end wave-uniform
// in registers via butterfly all-reduce), (3) ballot redistribute, (4) v5 scan.
// All LDS is wave-private -> within-wave program order, no __syncthreads anywhere.
__global__ __launch_bounds__(256) void bkt_fused_v7(
    const int* __restrict__ X, const int* __restrict__ y,
    const float* __restrict__ embed,
    const float* __restrict__ W0, const float* __restrict__ b0,
    const float* __restrict__ W1, const float* __restrict__ b1,
    const float* __restrict__ Wout, const float* __restrict__ bout,
    float* __restrict__ out_corr, float* __restrict__ out_lat)
{
    const int lane = threadIdx.x & 63;
    const int wid  = threadIdx.x >> 6;
    const int row  = blockIdx.x * 4 + wid;

    __shared__ float hstage[4][64];            // 1 KB: MLP activation broadcast
    __shared__ float trbuf[4][2][64 * 17];     // 34816 B: transpose buffers
    float* hbuf = hstage[wid];
    float* shc  = trbuf[wid][0];
    float* shl  = trbuf[wid][1];

    // ---- Phase A: issue coalesced y loads first (latency hides under MLP) ----
    const int4* yrow = (const int4*)(y + (size_t)row * TSTEPS);
    const int4 vy0 = yrow[0 * 64 + lane];
    const int4 vy1 = yrow[1 * 64 + lane];
    const int4 vy2 = yrow[2 * 64 + lane];
    const int4 vy3 = yrow[3 * 64 + lane];

    // ---- Phase B: solo per-wave MLP for this row ----
    const int skill = X[row];
    hbuf[lane] = embed[(size_t)skill * 64 + lane];   // wave-private: no barrier
    float acc = b0[lane];
    #pragma unroll
    for (int k4 = 0; k4 < 16; ++k4) {
        const float4 e = *(const float4*)&hbuf[k4 * 4];   // LDS broadcast read
        acc = fmaf(e.x, W0[(k4 * 4 + 0) * 64 + lane], acc);
        acc = fmaf(e.y, W0[(k4 * 4 + 1) * 64 + lane], acc);
        acc = fmaf(e.z, W0[(k4 * 4 + 2) * 64 + lane], acc);
        acc = fmaf(e.w, W0[(k4 * 4 + 3) * 64 + lane], acc);
    }
    hbuf[lane] = fmaxf(acc, 0.f);                     // overwrite: program order
    acc = b1[lane];
    #pragma unroll
    for (int k4 = 0; k4 < 16; ++k4) {
        const float4 e = *(const float4*)&hbuf[k4 * 4];
        acc = fmaf(e.x, W1[(k4 * 4 + 0) * 64 + lane], acc);
        acc = fmaf(e.y, W1[(k4 * 4 + 1) * 64 + lane], acc);
        acc = fmaf(e.z, W1[(k4 * 4 + 2) * 64 + lane], acc);
        acc = fmaf(e.w, W1[(k4 * 4 + 3) * 64 + lane], acc);
    }
    const float h2 = fmaxf(acc, 0.f);

    const float4 wo = ((const float4*)Wout)[lane];
    float p0 = h2 * wo.x, p1 = h2 * wo.y, p2 = h2 * wo.z, p3 = h2 * wo.w;
    #pragma unroll
    for (int off = 32; off >= 1; off >>= 1) {
        p0 += __shfl_xor(p0, off, 64);
        p1 += __shfl_xor(p1, off, 64);
        p2 += __shfl_xor(p2, off, 64);
        p3 += __shfl_xor(p3, off, 64);
    }
    const float4 bo = *(const float4*)bout;
    const float l     = clampP(sigm(p0 + bo.x));
    const float g     = clampP(sigm(p1 + bo.y));
    const float s     = clampP(sigm(p2 + bo.z));
    const float prior = clampP(sigm(p3 + bo.w));

    // ---- ballot bit-redistribution: chunk c = lane owns t = 16c+q ----
    unsigned long long B_[4][4];
    B_[0][0] = __ballot(vy0.x > 0); B_[0][1] = __ballot(vy0.y > 0);
    B_[0][2] = __ballot(vy0.z > 0); B_[0][3] = __ballot(vy0.w > 0);
    B_[1][0] = __ballot(vy1.x > 0); B_[1][1] = __ballot(vy1.y > 0);
    B_[1][2] = __ballot(vy1.z > 0); B_[1][3] = __ballot(vy1.w > 0);
    B_[2][0] = __ballot(vy2.x > 0); B_[2][1] = __ballot(vy2.y > 0);
    B_[2][2] = __ballot(vy2.z > 0); B_[2][3] = __ballot(vy2.w > 0);
    B_[3][0] = __ballot(vy3.x > 0); B_[3][1] = __ballot(vy3.y > 0);
    B_[3][2] = __ballot(vy3.z > 0); B_[3][3] = __ballot(vy3.w > 0);
    const int jsel  = lane >> 4;
    const int ibase = (lane & 15) * 4;
    unsigned msk = 0;
    #pragma unroll
    for (int e = 0; e < 4; ++e) {
        const unsigned long long be =
            (jsel == 0) ? B_[0][e] : (jsel == 1) ? B_[1][e] :
            (jsel == 2) ? B_[2][e] : B_[3][e];
        const unsigned n  = (unsigned)(be >> ibase) & 0xFu;
        const unsigned sp = (n & 1u) | ((n & 2u) << 3) | ((n & 4u) << 6) | ((n & 8u) << 9);
        msk |= sp << e;
    }

    // step as Mobius: L' = (m00*L+m01)/(m10*L+m11)
    const float c1 = 1.f - s - g, d1 = g;             // y=1 denominator coeffs
    const float e00_1 = fmaf(l, c1, (1.f - l) * (1.f - s));
    const float e01_1 = l * d1;
    const float c0 = s + g - 1.f, d0 = 1.f - g;       // y=0
    const float e00_0 = fmaf(l, c0, (1.f - l) * s);
    const float e01_0 = l * d0;

    // Phase C: compose my chunk's 16 step matrices (renorm every 4; m11 > 0)
    float m00 = 1.f, m01 = 0.f, m10 = 0.f, m11 = 1.f;
    #pragma unroll
    for (int t = 0; t < CLEN; ++t) {
        const bool one = (msk >> t) & 1u;
        const float e00 = one ? e00_1 : e00_0;
        const float e01 = one ? e01_1 : e01_0;
        const float e10 = one ? c1 : c0;
        const float e11 = one ? d1 : d0;
        const float n00 = fmaf(e00, m00, e01 * m10);
        const float n01 = fmaf(e00, m01, e01 * m11);
        const float n10 = fmaf(e10, m00, e11 * m10);
        const float n11 = fmaf(e10, m01, e11 * m11);
        if ((t & 3) == 3) {
            const float inv = __builtin_amdgcn_rcpf(n11);
            m00 = n00 * inv; m01 = n01 * inv; m10 = n10 * inv; m11 = 1.f;
        } else {
            m00 = n00; m01 = n01; m10 = n10; m11 = n11;
        }
    }

    // Phase D: inclusive Hillis-Steele prefix over the 64 chunk matrices
    float s00 = m00, s01 = m01, s10 = m10, s11 = m11;
    #pragma unroll
    for (int d = 1; d < 64; d <<= 1) {
        const float t00 = __shfl_up(s00, d, 64);
        const float t01 = __shfl_up(s01, d, 64);
        const float t10 = __shfl_up(s10, d, 64);
        const float t11 = __shfl_up(s11, d, 64);
        if (lane >= d) {
            const float r00 = fmaf(s00, t00, s01 * t10);
            const float r01 = fmaf(s00, t01, s01 * t11);
            const float r10 = fmaf(s10, t00, s11 * t10);
            const float r11 = fmaf(s10, t01, s11 * t11);
            const float inv = __builtin_amdgcn_rcpf(r11);
            s00 = r00 * inv; s01 = r01 * inv; s10 = r10 * inv; s11 = 1.f;
        }
    }
    // exclusive prefix -> my chunk-start latent
    const float x00 = __shfl_up(s00, 1, 64);
    const float x01 = __shfl_up(s01, 1, 64);
    const float x10 = __shfl_up(s10, 1, 64);
    const float x11 = __shfl_up(s11, 1, 64);
    float L0;
    if (lane == 0) {
        L0 = prior;
    } else {
        const float num = fmaf(x00, prior, x01);
        const float den = fmaf(x10, prior, x11);
        L0 = clampP(num * __builtin_amdgcn_rcpf(den));
    }

    // Phase E: exact clipped recurrence; write both outputs through LDS (1 rcp/step)
    const float a   = 1.f - s;
    const float omg = 1.f - g;
    const float oml = 1.f - l;
    float Lc = L0;
    #pragma unroll
    for (int t = 0; t < CLEN; ++t) {
        const float correct = fmaf(Lc, c1, g);    // L*(1-s-g)+g
        const float den0    = fmaf(Lc, c0, omg);  // L*(s+g-1)+(1-g)
        shc[lane * 17 + t] = correct;
        shl[lane * 17 + t] = Lc;
        const bool one = (msk >> t) & 1u;
        const float den = one ? correct : den0;
        const float num = Lc * (one ? a : s);
        const float k   = num * __builtin_amdgcn_rcpf(den);
        Lc = clampP(fmaf(k, oml, l));
    }

    // Phase F: transpose (chunk-major -> time-major) + coalesced 1KB stores
    float* oc = out_corr + (size_t)row * TSTEPS;
    float* ol = out_lat  + (size_t)row * TSTEPS;
    #pragma unroll
    for (int j = 0; j < 4; ++j) {
        const int c    = j * 16 + (lane >> 2);
        const int q    = (lane & 3) * 4;
        const int base = c * 17 + q;
        float4 vc, vl;
        vc.x = shc[base + 0]; vc.y = shc[base + 1]; vc.z = shc[base + 2]; vc.w = shc[base + 3];
        vl.x = shl[base + 0]; vl.y = shl[base + 1]; vl.z = shl[base + 2]; vl.w = shl[base + 3];
        *(float4*)(oc + j * 256 + lane * 4) = vc;
        *(float4*)(ol + j * 256 + lane * 4) = vl;
    }
}

extern "C" void kernel_launch(void* const* d_in, const int* in_sizes, int n_in,
                              void* d_out, int out_size, void* d_ws, size_t ws_size,
                              hipStream_t stream) {
    const int*   X     = (const int*)  d_in[0];
    const int*   y     = (const int*)  d_in[1];
    const float* embed = (const float*)d_in[2];
    const float* W0    = (const float*)d_in[3];
    const float* b0    = (const float*)d_in[4];
    const float* W1    = (const float*)d_in[5];
    const float* b1    = (const float*)d_in[6];
    const float* Wout  = (const float*)d_in[7];
    const float* bout  = (const float*)d_in[8];

    float* out_corr = (float*)d_out;
    float* out_lat  = out_corr + (size_t)NROWS * TSTEPS;

    bkt_fused_v7<<<NROWS / 4, 256, 0, stream>>>(
        X, y, embed, W0, b0, W1, b1, Wout, bout, out_corr, out_lat);
}

// Round 5
// 119.445 us; speedup vs baseline: 1.0632x; 1.0191x over previous
//
#include <hip/hip_runtime.h>

#define TSTEPS 1024
#define NROWS  8192
#define CLEN   16      // steps per chunk = steps per lane
#define KEPS   1e-6f

__device__ __forceinline__ float clampP(float x) {
    return fminf(fmaxf(x, KEPS), 1.f - KEPS);
}
__device__ __forceinline__ float sigm(float v) {
    return 1.0f / (1.0f + __expf(-v));
}

// Fold 16 ballots (one row's y bits, load-order) into this lane's 16-step chunk mask.
// chunk c = lane owns t = 16c+q. bit q lives at ballot[j=c>>4][e=q&3],
// bit index 4*(c&15) + (q>>2). Gather 4-bit nibble per e, spread k->4k.
__device__ __forceinline__ unsigned fold_msk(
    const unsigned long long B0[4], const unsigned long long B1[4],
    const unsigned long long B2[4], const unsigned long long B3[4],
    int jsel, int ibase)
{
    unsigned msk = 0;
    #pragma unroll
    for (int e = 0; e < 4; ++e) {
        const unsigned long long be =
            (jsel == 0) ? B0[e] : (jsel == 1) ? B1[e] :
            (jsel == 2) ? B2[e] : B3[e];
        const unsigned n  = (unsigned)(be >> ibase) & 0xFu;
        const unsigned sp = (n & 1u) | ((n & 2u) << 3) | ((n & 4u) << 6) | ((n & 8u) << 9);
        msk |= sp << e;
    }
    return msk;
}

// ---------------- Fused kernel v8: one wave per TWO rows, zero barriers ----------------
// 2-way ILP on every serial chain (MLP FMA chain, butterfly, scan, recurrence);
// weight loads shared between the two rows. All LDS wave-private -> program order,
// no __syncthreads anywhere. Grid = exactly one co-resident batch (4 blocks/CU).
__global__ __launch_bounds__(256) void bkt_fused_v8(
    const int* __restrict__ X, const int* __restrict__ y,
    const float* __restrict__ embed,
    const float* __restrict__ W0, const float* __restrict__ b0,
    const float* __restrict__ W1, const float* __restrict__ b1,
    const float* __restrict__ Wout, const float* __restrict__ bout,
    float* __restrict__ out_corr, float* __restrict__ out_lat)
{
    const int lane = threadIdx.x & 63;
    const int wid  = threadIdx.x >> 6;
    const int rowA = blockIdx.x * 8 + wid * 2;
    const int rowB = rowA + 1;

    __shared__ float hstage[4][2][64];         // 2 KB: MLP activation broadcast
    __shared__ float trbuf[4][2][64 * 17];     // 34816 B: transpose buffers (reused A then B)
    float* hA  = hstage[wid][0];
    float* hB  = hstage[wid][1];
    float* shc = trbuf[wid][0];
    float* shl = trbuf[wid][1];

    // ---- Phase A: issue coalesced y loads for both rows ----
    const int4* yA = (const int4*)(y + (size_t)rowA * TSTEPS);
    const int4* yB = (const int4*)(y + (size_t)rowB * TSTEPS);
    const int4 va0 = yA[0 * 64 + lane], va1 = yA[1 * 64 + lane];
    const int4 va2 = yA[2 * 64 + lane], va3 = yA[3 * 64 + lane];
    const int4 vb0 = yB[0 * 64 + lane], vb1 = yB[1 * 64 + lane];
    const int4 vb2 = yB[2 * 64 + lane], vb3 = yB[3 * 64 + lane];

    // issue embed loads (latency overlaps the ballot folding below)
    const int skA = X[rowA], skB = X[rowB];
    const float emA = embed[(size_t)skA * 64 + lane];
    const float emB = embed[(size_t)skB * 64 + lane];

    // ---- fold ballots now (frees all y registers before the MLP) ----
    const int jsel  = lane >> 4;
    const int ibase = (lane & 15) * 4;
    unsigned mskA, mskB;
    {
        unsigned long long A0[4] = { __ballot(va0.x > 0), __ballot(va0.y > 0),
                                     __ballot(va0.z > 0), __ballot(va0.w > 0) };
        unsigned long long A1[4] = { __ballot(va1.x > 0), __ballot(va1.y > 0),
                                     __ballot(va1.z > 0), __ballot(va1.w > 0) };
        unsigned long long A2[4] = { __ballot(va2.x > 0), __ballot(va2.y > 0),
                                     __ballot(va2.z > 0), __ballot(va2.w > 0) };
        unsigned long long A3[4] = { __ballot(va3.x > 0), __ballot(va3.y > 0),
                                     __ballot(va3.z > 0), __ballot(va3.w > 0) };
        mskA = fold_msk(A0, A1, A2, A3, jsel, ibase);
    }
    {
        unsigned long long C0[4] = { __ballot(vb0.x > 0), __ballot(vb0.y > 0),
                                     __ballot(vb0.z > 0), __ballot(vb0.w > 0) };
        unsigned long long C1[4] = { __ballot(vb1.x > 0), __ballot(vb1.y > 0),
                                     __ballot(vb1.z > 0), __ballot(vb1.w > 0) };
        unsigned long long C2[4] = { __ballot(vb2.x > 0), __ballot(vb2.y > 0),
                                     __ballot(vb2.z > 0), __ballot(vb2.w > 0) };
        unsigned long long C3[4] = { __ballot(vb3.x > 0), __ballot(vb3.y > 0),
                                     __ballot(vb3.z > 0), __ballot(vb3.w > 0) };
        mskB = fold_msk(C0, C1, C2, C3, jsel, ibase);
    }

    // ---- Phase B: MLP for both rows, shared weight loads (2 indep FMA chains) ----
    hA[lane] = emA;                              // wave-private: no barrier
    hB[lane] = emB;
    float accA = b0[lane], accB = accA;
    #pragma unroll
    for (int k4 = 0; k4 < 16; ++k4) {
        const float4 eA = *(const float4*)&hA[k4 * 4];
        const float4 eB = *(const float4*)&hB[k4 * 4];
        const float w0 = W0[(k4 * 4 + 0) * 64 + lane];
        const float w1 = W0[(k4 * 4 + 1) * 64 + lane];
        const float w2 = W0[(k4 * 4 + 2) * 64 + lane];
        const float w3 = W0[(k4 * 4 + 3) * 64 + lane];
        accA = fmaf(eA.x, w0, accA); accA = fmaf(eA.y, w1, accA);
        accA = fmaf(eA.z, w2, accA); accA = fmaf(eA.w, w3, accA);
        accB = fmaf(eB.x, w0, accB); accB = fmaf(eB.y, w1, accB);
        accB = fmaf(eB.z, w2, accB); accB = fmaf(eB.w, w3, accB);
    }
    hA[lane] = fmaxf(accA, 0.f);                 // overwrite: program order
    hB[lane] = fmaxf(accB, 0.f);
    accA = b1[lane]; accB = accA;
    #pragma unroll
    for (int k4 = 0; k4 < 16; ++k4) {
        const float4 eA = *(const float4*)&hA[k4 * 4];
        const float4 eB = *(const float4*)&hB[k4 * 4];
        const float w0 = W1[(k4 * 4 + 0) * 64 + lane];
        const float w1 = W1[(k4 * 4 + 1) * 64 + lane];
        const float w2 = W1[(k4 * 4 + 2) * 64 + lane];
        const float w3 = W1[(k4 * 4 + 3) * 64 + lane];
        accA = fmaf(eA.x, w0, accA); accA = fmaf(eA.y, w1, accA);
        accA = fmaf(eA.z, w2, accA); accA = fmaf(eA.w, w3, accA);
        accB = fmaf(eB.x, w0, accB); accB = fmaf(eB.y, w1, accB);
        accB = fmaf(eB.z, w2, accB); accB = fmaf(eB.w, w3, accB);
    }
    const float h2A = fmaxf(accA, 0.f);
    const float h2B = fmaxf(accB, 0.f);

    const float4 wo = ((const float4*)Wout)[lane];
    float pA0 = h2A * wo.x, pA1 = h2A * wo.y, pA2 = h2A * wo.z, pA3 = h2A * wo.w;
    float pB0 = h2B * wo.x, pB1 = h2B * wo.y, pB2 = h2B * wo.z, pB3 = h2B * wo.w;
    #pragma unroll
    for (int off = 32; off >= 1; off >>= 1) {
        pA0 += __shfl_xor(pA0, off, 64);
        pA1 += __shfl_xor(pA1, off, 64);
        pA2 += __shfl_xor(pA2, off, 64);
        pA3 += __shfl_xor(pA3, off, 64);
        pB0 += __shfl_xor(pB0, off, 64);
        pB1 += __shfl_xor(pB1, off, 64);
        pB2 += __shfl_xor(pB2, off, 64);
        pB3 += __shfl_xor(pB3, off, 64);
    }
    const float4 bo = *(const float4*)bout;
    const float lA     = clampP(sigm(pA0 + bo.x));
    const float gA     = clampP(sigm(pA1 + bo.y));
    const float sA     = clampP(sigm(pA2 + bo.z));
    const float priorA = clampP(sigm(pA3 + bo.w));
    const float lB     = clampP(sigm(pB0 + bo.x));
    const float gB     = clampP(sigm(pB1 + bo.y));
    const float sB     = clampP(sigm(pB2 + bo.z));
    const float priorB = clampP(sigm(pB3 + bo.w));

    // Mobius step coefficients per row: L' = (m00*L+m01)/(m10*L+m11)
    const float c1A = 1.f - sA - gA, d1A = gA;
    const float e00_1A = fmaf(lA, c1A, (1.f - lA) * (1.f - sA));
    const float e01_1A = lA * d1A;
    const float c0A = sA + gA - 1.f, d0A = 1.f - gA;
    const float e00_0A = fmaf(lA, c0A, (1.f - lA) * sA);
    const float e01_0A = lA * d0A;

    const float c1B = 1.f - sB - gB, d1B = gB;
    const float e00_1B = fmaf(lB, c1B, (1.f - lB) * (1.f - sB));
    const float e01_1B = lB * d1B;
    const float c0B = sB + gB - 1.f, d0B = 1.f - gB;
    const float e00_0B = fmaf(lB, c0B, (1.f - lB) * sB);
    const float e01_0B = lB * d0B;

    // ---- Phase C: compose 16 step matrices per row (interleaved chains) ----
    float mA00 = 1.f, mA01 = 0.f, mA10 = 0.f, mA11 = 1.f;
    float mB00 = 1.f, mB01 = 0.f, mB10 = 0.f, mB11 = 1.f;
    #pragma unroll
    for (int t = 0; t < CLEN; ++t) {
        {
            const bool one = (mskA >> t) & 1u;
            const float e00 = one ? e00_1A : e00_0A;
            const float e01 = one ? e01_1A : e01_0A;
            const float e10 = one ? c1A : c0A;
            const float e11 = one ? d1A : d0A;
            const float n00 = fmaf(e00, mA00, e01 * mA10);
            const float n01 = fmaf(e00, mA01, e01 * mA11);
            const float n10 = fmaf(e10, mA00, e11 * mA10);
            const float n11 = fmaf(e10, mA01, e11 * mA11);
            if ((t & 3) == 3) {
                const float inv = __builtin_amdgcn_rcpf(n11);
                mA00 = n00 * inv; mA01 = n01 * inv; mA10 = n10 * inv; mA11 = 1.f;
            } else {
                mA00 = n00; mA01 = n01; mA10 = n10; mA11 = n11;
            }
        }
        {
            const bool one = (mskB >> t) & 1u;
            const float e00 = one ? e00_1B : e00_0B;
            const float e01 = one ? e01_1B : e01_0B;
            const float e10 = one ? c1B : c0B;
            const float e11 = one ? d1B : d0B;
            const float n00 = fmaf(e00, mB00, e01 * mB10);
            const float n01 = fmaf(e00, mB01, e01 * mB11);
            const float n10 = fmaf(e10, mB00, e11 * mB10);
            const float n11 = fmaf(e10, mB01, e11 * mB11);
            if ((t & 3) == 3) {
                const float inv = __builtin_amdgcn_rcpf(n11);
                mB00 = n00 * inv; mB01 = n01 * inv; mB10 = n10 * inv; mB11 = 1.f;
            } else {
                mB00 = n00; mB01 = n01; mB10 = n10; mB11 = n11;
            }
        }
    }

    // ---- Phase D: inclusive Hillis-Steele prefix over 64 chunk matrices, both rows ----
    float sA00 = mA00, sA01 = mA01, sA10 = mA10, sA11 = mA11;
    float sB00 = mB00, sB01 = mB01, sB10 = mB10, sB11 = mB11;
    #pragma unroll
    for (int d = 1; d < 64; d <<= 1) {
        const float tA00 = __shfl_up(sA00, d, 64);
        const float tA01 = __shfl_up(sA01, d, 64);
        const float tA10 = __shfl_up(sA10, d, 64);
        const float tA11 = __shfl_up(sA11, d, 64);
        const float tB00 = __shfl_up(sB00, d, 64);
        const float tB01 = __shfl_up(sB01, d, 64);
        const float tB10 = __shfl_up(sB10, d, 64);
        const float tB11 = __shfl_up(sB11, d, 64);
        if (lane >= d) {
            {
                const float r00 = fmaf(sA00, tA00, sA01 * tA10);
                const float r01 = fmaf(sA00, tA01, sA01 * tA11);
                const float r10 = fmaf(sA10, tA00, sA11 * tA10);
                const float r11 = fmaf(sA10, tA01, sA11 * tA11);
                const float inv = __builtin_amdgcn_rcpf(r11);
                sA00 = r00 * inv; sA01 = r01 * inv; sA10 = r10 * inv; sA11 = 1.f;
            }
            {
                const float r00 = fmaf(sB00, tB00, sB01 * tB10);
                const float r01 = fmaf(sB00, tB01, sB01 * tB11);
                const float r10 = fmaf(sB10, tB00, sB11 * tB10);
                const float r11 = fmaf(sB10, tB01, sB11 * tB11);
                const float inv = __builtin_amdgcn_rcpf(r11);
                sB00 = r00 * inv; sB01 = r01 * inv; sB10 = r10 * inv; sB11 = 1.f;
            }
        }
    }
    // exclusive prefix -> chunk-start latents
    const float xA00 = __shfl_up(sA00, 1, 64);
    const float xA01 = __shfl_up(sA01, 1, 64);
    const float xA10 = __shfl_up(sA10, 1, 64);
    const float xA11 = __shfl_up(sA11, 1, 64);
    const float xB00 = __shfl_up(sB00, 1, 64);
    const float xB01 = __shfl_up(sB01, 1, 64);
    const float xB10 = __shfl_up(sB10, 1, 64);
    const float xB11 = __shfl_up(sB11, 1, 64);
    float L0A, L0B;
    if (lane == 0) {
        L0A = priorA;
        L0B = priorB;
    } else {
        const float numA = fmaf(xA00, priorA, xA01);
        const float denA = fmaf(xA10, priorA, xA11);
        L0A = clampP(numA * __builtin_amdgcn_rcpf(denA));
        const float numB = fmaf(xB00, priorB, xB01);
        const float denB = fmaf(xB10, priorB, xB11);
        L0B = clampP(numB * __builtin_amdgcn_rcpf(denB));
    }

    // ---- Phase E: interleaved recurrences. A writes through to LDS; B to registers ----
    const float aA = 1.f - sA, omgA = 1.f - gA, omlA = 1.f - lA;
    const float aB = 1.f - sB, omgB = 1.f - gB, omlB = 1.f - lB;
    float crB[CLEN], ltB[CLEN];
    float LcA = L0A, LcB = L0B;
    #pragma unroll
    for (int t = 0; t < CLEN; ++t) {
        {
            const float correct = fmaf(LcA, c1A, gA);
            const float den0    = fmaf(LcA, c0A, omgA);
            shc[lane * 17 + t] = correct;
            shl[lane * 17 + t] = LcA;
            const bool one = (mskA >> t) & 1u;
            const float den = one ? correct : den0;
            const float num = LcA * (one ? aA : sA);
            const float k   = num * __builtin_amdgcn_rcpf(den);
            LcA = clampP(fmaf(k, omlA, lA));
        }
        {
            const float correct = fmaf(LcB, c1B, gB);
            const float den0    = fmaf(LcB, c0B, omgB);
            crB[t] = correct;
            ltB[t] = LcB;
            const bool one = (mskB >> t) & 1u;
            const float den = one ? correct : den0;
            const float num = LcB * (one ? aB : sB);
            const float k   = num * __builtin_amdgcn_rcpf(den);
            LcB = clampP(fmaf(k, omlB, lB));
        }
    }

    // ---- Phase F-A: transpose + coalesced 1KB stores for row A ----
    float* ocA = out_corr + (size_t)rowA * TSTEPS;
    float* olA = out_lat  + (size_t)rowA * TSTEPS;
    #pragma unroll
    for (int j = 0; j < 4; ++j) {
        const int c    = j * 16 + (lane >> 2);
        const int q    = (lane & 3) * 4;
        const int base = c * 17 + q;
        float4 vc, vl;
        vc.x = shc[base + 0]; vc.y = shc[base + 1]; vc.z = shc[base + 2]; vc.w = shc[base + 3];
        vl.x = shl[base + 0]; vl.y = shl[base + 1]; vl.z = shl[base + 2]; vl.w = shl[base + 3];
        *(float4*)(ocA + j * 256 + lane * 4) = vc;
        *(float4*)(olA + j * 256 + lane * 4) = vl;
    }

    // ---- Phase F-B: refill the same buffers from registers, then store row B ----
    // (same-wave DS ordering: these writes cannot pass the reads above)
    #pragma unroll
    for (int t = 0; t < CLEN; ++t) {
        shc[lane * 17 + t] = crB[t];
        shl[lane * 17 + t] = ltB[t];
    }
    float* ocB = out_corr + (size_t)rowB * TSTEPS;
    float* olB = out_lat  + (size_t)rowB * TSTEPS;
    #pragma unroll
    for (int j = 0; j < 4; ++j) {
        const int c    = j * 16 + (lane >> 2);
        const int q    = (lane & 3) * 4;
        const int base = c * 17 + q;
        float4 vc, vl;
        vc.x = shc[base + 0]; vc.y = shc[base + 1]; vc.z = shc[base + 2]; vc.w = shc[base + 3];
        vl.x = shl[base + 0]; vl.y = shl[base + 1]; vl.z = shl[base + 2]; vl.w = shl[base + 3];
        *(float4*)(ocB + j * 256 + lane * 4) = vc;
        *(float4*)(olB + j * 256 + lane * 4) = vl;
    }
}

extern "C" void kernel_launch(void* const* d_in, const int* in_sizes, int n_in,
                              void* d_out, int out_size, void* d_ws, size_t ws_size,
                              hipStream_t stream) {
    const int*   X     = (const int*)  d_in[0];
    const int*   y     = (const int*)  d_in[1];
    const float* embed = (const float*)d_in[2];
    const float* W0    = (const float*)d_in[3];
    const float* b0    = (const float*)d_in[4];
    const float* W1    = (const float*)d_in[5];
    const float* b1    = (const float*)d_in[6];
    const float* Wout  = (const float*)d_in[7];
    const float* bout  = (const float*)d_in[8];

    float* out_corr = (float*)d_out;
    float* out_lat  = out_corr + (size_t)NROWS * TSTEPS;

    bkt_fused_v8<<<NROWS / 8, 256, 0, stream>>>(
        X, y, embed, W0, b0, W1, b1, Wout, bout, out_corr, out_lat);
}